// Round 5
// baseline (5343.133 us; speedup 1.0000x reference)
//
#include <hip/hip_runtime.h>
#include <stdint.h>

#define HID   512
#define SEQT  512
#define NB    32            // batches per group
#define L1_RB 2064          // LDS row stride B, layer1: 2048 data + 16 pad
#define L0_RB 1072          // LDS row stride B, layer0: 1024 h0 + 16 u + 16 zeros + 16 pad
#define BUF1_U64 65536      // 256 rows * 256 u64 per h buffer
#define FPAD 16             // flags padded to 64B (16 ints)

typedef __attribute__((ext_vector_type(8)))  __bf16 bf16x8;
typedef __attribute__((ext_vector_type(16))) float  f32x16;
typedef unsigned long long u64;

__device__ __forceinline__ unsigned short f2bf(float x) {
  union { float f; unsigned u; } v; v.f = x;
  return (unsigned short)((v.u + 0x7FFFu + ((v.u >> 16) & 1u)) >> 16);  // RNE
}
__device__ __forceinline__ float bf2f(unsigned short h) {
  union { unsigned u; float f; } v; v.u = ((unsigned)h) << 16;
  return v.f;
}
__device__ __forceinline__ float sigm(float x)     { return 1.0f / (1.0f + __expf(-x)); }
__device__ __forceinline__ float tanhfast(float x) { return 2.0f / (1.0f + __expf(-2.0f * x)) - 1.0f; }

__device__ __forceinline__ u64 ld_agent(const u64* p) {
  return __hip_atomic_load(p, __ATOMIC_RELAXED, __HIP_MEMORY_SCOPE_AGENT);
}
__device__ __forceinline__ void st_agent(u64* p, u64 v) {
  __hip_atomic_store(p, v, __ATOMIC_RELAXED, __HIP_MEMORY_SCOPE_AGENT);
}
__device__ __forceinline__ void atom_inc_agent(u64* p) {
  __hip_atomic_fetch_add(p, 1ull, __ATOMIC_RELAXED, __HIP_MEMORY_SCOPE_AGENT);
}

// async global->LDS DMA, 16B/lane, cpol sc0|sc1 (0x11): bypass L1+L2, read at
// the IF$ coherence point. No VGPR round trip -> fully vmcnt-pipelined.
__device__ __forceinline__ void dma16(const void* g, void* l) {
  __builtin_amdgcn_global_load_lds((const unsigned int*)g, (unsigned int*)l, 16, 0, 0x11);
}

// 256 blocks = 8 groups x 32 (16 layer0 + 16 layer1), 32 batches/group.
// Weights in registers; per tick: DMA-stage group h-tile to LDS, MFMA (dual acc
// chains), lane-local cell update, sc1 h-store.
// Tick barrier (new): ONE monotonic u64 counter per group. Each wave drains its
// own stores (vmcnt(0)) then atomic-adds 1; all waves poll the single line for
// count >= 128*(t+1). Safe without __syncthreads: a wave's LDS reads retire
// before its atomic, so no wave can overwrite LDS that a peer still needs.
// Boot barrier keeps the proven per-block-flag protocol (handles ws poison).
__global__ __launch_bounds__(256, 1) void lstm_persist(
    const float* __restrict__ u_seq,
    const float* __restrict__ w_ih_0, const float* __restrict__ w_hh_0,
    const float* __restrict__ b_ih_0, const float* __restrict__ b_hh_0,
    const float* __restrict__ w_ih_1, const float* __restrict__ w_hh_1,
    const float* __restrict__ b_ih_1, const float* __restrict__ b_hh_1,
    const float* __restrict__ fc_w0, const float* __restrict__ fc_b0,
    const float* __restrict__ fc_w1, const float* __restrict__ fc_b1,
    float* __restrict__ out, int* flags, u64* hbuf)
{
  extern __shared__ char smemc[];    // B-tile staging (66048 B for L1 blocks)

  const int bid  = blockIdx.x;
  const int g    = bid >> 5;            // group 0..7
  const int rr   = bid & 31;            // rank in group
  const int isL1 = rr >> 4;
  const int rl   = rr & 15;             // rank within layer
  const int tid  = threadIdx.x;
  const int wv   = tid >> 6;
  const int lane = tid & 63;
  const int lcol = lane & 31;           // A row (gate row) / B col (batch)
  const int kh   = lane >> 5;           // K-half within MFMA step
  const int batch0 = g * NB;

  const int unit_base = rl * 32 + wv * 8;       // 8 units per wave
  const int prow = unit_base * 4 + lcol;        // permuted gate row (4u+gate)
  const int orig = (prow & 3) * HID + (prow >> 2);

  // group tick counter: bytes [32,40) of group-leader block's 64B flag line
  u64* gcnt = (u64*)((char*)flags + (size_t)(g * 32) * 64 + 32);

  // boot barrier (proven flag protocol; handles 0xAA ws poison)
  auto groupbar = [&](int gen) {
    __syncthreads();   // drains vmcnt before flag store
    if (tid == 0)
      __hip_atomic_store(&flags[bid * FPAD], gen, __ATOMIC_RELAXED, __HIP_MEMORY_SCOPE_AGENT);
    if (tid < 32) {
      const int* fl = flags + (g * 32 + tid) * FPAD;
      while (__hip_atomic_load(fl, __ATOMIC_RELAXED, __HIP_MEMORY_SCOPE_AGENT) < gen)
        __builtin_amdgcn_s_sleep(1);
    }
    __syncthreads();
  };

  // steady-state tick barrier: per-wave drain + atomic arrival, 1-line poll
  auto tickbar = [&](int t) {
    asm volatile("s_waitcnt vmcnt(0)" ::: "memory");   // own h-stores acked
    if (lane == 0) atom_inc_agent(gcnt);
    asm volatile("s_waitcnt vmcnt(0)" ::: "memory");   // atomic issued & done
    const u64 target = (u64)(t + 1) * 128;             // 32 blocks * 4 waves
    while (ld_agent(gcnt) < target)
      __builtin_amdgcn_s_sleep(1);
    asm volatile("" ::: "memory");
  };

  // ---- zero both h buffers (ws poisoned 0xAA) + group counter ----
  {
    u64* p = hbuf + (size_t)bid * 512;
    st_agent(p + tid, 0);
    st_agent(p + tid + 256, 0);
  }
  if (rr == 0 && tid == 0) st_agent(gcnt, 0);
  groupbar(1);

  if (isL1) {
    // ================= LAYER 1 BLOCK =================
    bf16x8 w[64];   // A-frags resident: 256 regs (unified VGPR/AGPR file, 1 wave/SIMD)
    {
      const float* bih = w_ih_1 + (size_t)orig * HID;   // k<512: input = h0
      const float* bhh = w_hh_1 + (size_t)orig * HID;   // k>=512: recurrent h1
#pragma unroll
      for (int s = 0; s < 64; ++s) {
        int k = s * 16 + kh * 8;
        const float* src = (k < HID) ? (bih + k) : (bhh + (k - HID));
        float4 f0 = *(const float4*)src, f1 = *(const float4*)(src + 4);
        union { bf16x8 v; unsigned short h[8]; } u;
        u.h[0]=f2bf(f0.x); u.h[1]=f2bf(f0.y); u.h[2]=f2bf(f0.z); u.h[3]=f2bf(f0.w);
        u.h[4]=f2bf(f1.x); u.h[5]=f2bf(f1.y); u.h[6]=f2bf(f1.z); u.h[7]=f2bf(f1.w);
        w[s] = u.v;
      }
    }
    float bias[16];
#pragma unroll
    for (int rg = 0; rg < 16; ++rg) {
      int unit = unit_base + 2 * (rg >> 2) + kh;
      int gi = (rg & 3) * HID + unit;
      bias[rg] = b_ih_1[gi] + b_hh_1[gi];
    }
    float cc[4] = {0.f, 0.f, 0.f, 0.f};

    for (int tau = 0; tau <= SEQT; ++tau) {
      const char* curb = (const char*)(hbuf + ((tau & 1) ? BUF1_U64 : 0));
      u64*        nxt  = hbuf + ((tau & 1) ? 0 : BUF1_U64);
      if (tau >= 1) {
        // DMA-stage 32 rows x 2KB; wave wv handles rows wv*8..wv*8+7.
        // Chunk-1 (row bytes [0,1024) = MFMA s 0..31) issued FIRST so
        // vmcnt(8) certifies it while chunk-2 is still in flight.
#pragma unroll
        for (int j = 0; j < 8; ++j) {
          int b = wv * 8 + j;
          const char* gr = curb + ((size_t)(batch0 + b) << 11) + lane * 16;
          dma16(gr, smemc + b * L1_RB);
        }
#pragma unroll
        for (int j = 0; j < 8; ++j) {
          int b = wv * 8 + j;
          const char* gr = curb + ((size_t)(batch0 + b) << 11) + 1024 + lane * 16;
          dma16(gr, smemc + b * L1_RB + 1024);
        }
        f32x16 a0, a1;
#pragma unroll
        for (int i = 0; i < 16; ++i) { a0[i] = bias[i]; a1[i] = 0.f; }
        const char* brow = smemc + lcol * L1_RB + kh * 16;
        // phase 1: chunk-1 landed for all waves (own vmcnt(8) + barrier)
        asm volatile("s_waitcnt vmcnt(8)" ::: "memory");
        __builtin_amdgcn_s_barrier();
        asm volatile("" ::: "memory");
#pragma unroll
        for (int s = 0; s < 32; s += 2) {
          bf16x8 b0 = *(const bf16x8*)(brow + s * 32);
          bf16x8 b1 = *(const bf16x8*)(brow + s * 32 + 32);
          a0 = __builtin_amdgcn_mfma_f32_32x32x16_bf16(w[s],     b0, a0, 0, 0, 0);
          a1 = __builtin_amdgcn_mfma_f32_32x32x16_bf16(w[s + 1], b1, a1, 0, 0, 0);
        }
        // phase 2: chunk-2 landed (vmcnt(0) + barrier)
        asm volatile("s_waitcnt vmcnt(0)" ::: "memory");
        __builtin_amdgcn_s_barrier();
        asm volatile("" ::: "memory");
#pragma unroll
        for (int s = 32; s < 64; s += 2) {
          bf16x8 b0 = *(const bf16x8*)(brow + s * 32);
          bf16x8 b1 = *(const bf16x8*)(brow + s * 32 + 32);
          a0 = __builtin_amdgcn_mfma_f32_32x32x16_bf16(w[s],     b0, a0, 0, 0, 0);
          a1 = __builtin_amdgcn_mfma_f32_32x32x16_bf16(w[s + 1], b1, a1, 0, 0, 0);
        }
        float hv[4];
#pragma unroll
        for (int q = 0; q < 4; ++q) {
          float ig = sigm(a0[4 * q + 0] + a1[4 * q + 0]);
          float fg = sigm(a0[4 * q + 1] + a1[4 * q + 1]);
          float gg = tanhfast(a0[4 * q + 2] + a1[4 * q + 2]);
          float og = sigm(a0[4 * q + 3] + a1[4 * q + 3]);
          float c = fg * cc[q] + ig * gg;
          cc[q] = c;
          hv[q] = og * tanhfast(c);
        }
        unsigned own01 = (unsigned)f2bf(hv[0]) | ((unsigned)f2bf(hv[1]) << 16);
        unsigned own23 = (unsigned)f2bf(hv[2]) | ((unsigned)f2bf(hv[3]) << 16);
        unsigned p01 = (unsigned)__shfl_xor((int)own01, 32);
        unsigned p23 = (unsigned)__shfl_xor((int)own23, 32);
        if (kh == 0) {   // interleave even(own)/odd(partner) units -> 16B contiguous
          u64 q0 = ((u64)((own01 & 0xffffu) | ((p01 & 0xffffu) << 16)))
                 | (((u64)((own01 >> 16) | (p01 & 0xffff0000u))) << 32);
          u64 q1 = ((u64)((own23 & 0xffffu) | ((p23 & 0xffffu) << 16)))
                 | (((u64)((own23 >> 16) | (p23 & 0xffff0000u))) << 32);
          u64* orow = nxt + (size_t)(batch0 + lcol) * 256 + 128 + (unit_base >> 2);
          st_agent(orow, q0);
          st_agent(orow + 1, q1);
        }
      }
      tickbar(tau);
    }
  } else {
    // ================= LAYER 0 BLOCK =================
    bf16x8 w[33];
    {
      const float* bhh = w_hh_0 + (size_t)orig * HID;
#pragma unroll
      for (int s = 0; s < 32; ++s) {
        int k = s * 16 + kh * 8;
        float4 f0 = *(const float4*)(bhh + k), f1 = *(const float4*)(bhh + k + 4);
        union { bf16x8 v; unsigned short h[8]; } u;
        u.h[0]=f2bf(f0.x); u.h[1]=f2bf(f0.y); u.h[2]=f2bf(f0.z); u.h[3]=f2bf(f0.w);
        u.h[4]=f2bf(f1.x); u.h[5]=f2bf(f1.y); u.h[6]=f2bf(f1.z); u.h[7]=f2bf(f1.w);
        w[s] = u.v;
      }
      { // step 32: kh=0 -> u columns, kh=1 -> zeros (row pad region)
        union { bf16x8 v; unsigned short h[8]; } u;
        if (kh == 0) {
          const float* src = w_ih_0 + (size_t)orig * 8;
#pragma unroll
          for (int j = 0; j < 8; ++j) u.h[j] = f2bf(src[j]);
        } else {
#pragma unroll
          for (int j = 0; j < 8; ++j) u.h[j] = 0;
        }
        w[32] = u.v;
      }
    }
    float bias[16];
#pragma unroll
    for (int rg = 0; rg < 16; ++rg) {
      int unit = unit_base + 2 * (rg >> 2) + kh;
      int gi = (rg & 3) * HID + unit;
      bias[rg] = b_ih_0[gi] + b_hh_0[gi];
    }
    float cc[4] = {0.f, 0.f, 0.f, 0.f};

    // zeros for kh=1 of MFMA step 32: row bytes [1040,1056), written once
    if (tid < 64) *(u64*)(smemc + (tid >> 1) * L0_RB + 1040 + (tid & 1) * 8) = 0;

    // u prefetch: thread tid stages element (batch b, col i) each tick
    const int ub = tid >> 3, ui = tid & 7;
    const float* usrc = u_seq + (size_t)(batch0 + ub) * SEQT * 8 + ui;
    float unext = usrc[0];   // u(0); overlaps boot barrier

    for (int tau = 0; tau <= SEQT; ++tau) {
      const char* curb = (const char*)(hbuf + ((tau & 1) ? BUF1_U64 : 0));
      u64*        nxt  = hbuf + ((tau & 1) ? 0 : BUF1_U64);
      if (tau < SEQT) {
#pragma unroll
        for (int j = 0; j < 8; ++j) {
          int b = wv * 8 + j;
          const char* gr = curb + ((size_t)(batch0 + b) << 11) + lane * 16;
          dma16(gr, smemc + b * L0_RB);   // h0 half only (1KB)
        }
        // stage u_tau (prefetched last tick) into row bytes [1024,1040)
        ((unsigned short*)(smemc + ub * L0_RB))[512 + ui] = f2bf(unext);
        __syncthreads();
        f32x16 a0, a1;
#pragma unroll
        for (int i = 0; i < 16; ++i) { a0[i] = bias[i]; a1[i] = 0.f; }
        const char* brow = smemc + lcol * L0_RB + kh * 16;
#pragma unroll
        for (int s = 0; s < 32; s += 2) {
          bf16x8 b0 = *(const bf16x8*)(brow + s * 32);
          bf16x8 b1 = *(const bf16x8*)(brow + s * 32 + 32);
          a0 = __builtin_amdgcn_mfma_f32_32x32x16_bf16(w[s],     b0, a0, 0, 0, 0);
          a1 = __builtin_amdgcn_mfma_f32_32x32x16_bf16(w[s + 1], b1, a1, 0, 0, 0);
        }
        { // step 32: u fold (kh=0) / zeros (kh=1) at row offset 32*32
          bf16x8 b2 = *(const bf16x8*)(brow + 32 * 32);
          a0 = __builtin_amdgcn_mfma_f32_32x32x16_bf16(w[32], b2, a0, 0, 0, 0);
        }
        // prefetch u(tau+1): latency hides under update + barrier
        if (tau + 1 < SEQT) unext = usrc[(size_t)(tau + 1) * 8];
        float hv[4];
#pragma unroll
        for (int q = 0; q < 4; ++q) {
          float ig = sigm(a0[4 * q + 0] + a1[4 * q + 0]);
          float fg = sigm(a0[4 * q + 1] + a1[4 * q + 1]);
          float gg = tanhfast(a0[4 * q + 2] + a1[4 * q + 2]);
          float og = sigm(a0[4 * q + 3] + a1[4 * q + 3]);
          float c = fg * cc[q] + ig * gg;
          cc[q] = c;
          hv[q] = og * tanhfast(c);
        }
        unsigned own01 = (unsigned)f2bf(hv[0]) | ((unsigned)f2bf(hv[1]) << 16);
        unsigned own23 = (unsigned)f2bf(hv[2]) | ((unsigned)f2bf(hv[3]) << 16);
        unsigned p01 = (unsigned)__shfl_xor((int)own01, 32);
        unsigned p23 = (unsigned)__shfl_xor((int)own23, 32);
        if (kh == 0) {
          u64 q0 = ((u64)((own01 & 0xffffu) | ((p01 & 0xffffu) << 16)))
                 | (((u64)((own01 >> 16) | (p01 & 0xffff0000u))) << 32);
          u64 q1 = ((u64)((own23 & 0xffffu) | ((p23 & 0xffffu) << 16)))
                 | (((u64)((own23 >> 16) | (p23 & 0xffff0000u))) << 32);
          u64* orow = nxt + (size_t)(batch0 + lcol) * 256 + (unit_base >> 2);
          st_agent(orow, q0);
          st_agent(orow + 1, q1);
        }
      }
      tickbar(tau);
    }
  }

  // ---- FC head (fp32): block bid handles batch bid ----
  __syncthreads();   // all waves past final tickbar before LDS reuse
  {
    float* hT  = (float*)smemc;          // [512]
    float* hfc = ((float*)smemc) + 512;  // [256]
    const u64* hrow = hbuf + BUF1_U64 + (size_t)bid * 256 + 128;  // h1_{T-1} in buf1
    if (tid < 128) {
      u64 v = ld_agent(hrow + tid);
      const unsigned short* s4 = (const unsigned short*)&v;
      hT[tid * 4 + 0] = bf2f(s4[0]);
      hT[tid * 4 + 1] = bf2f(s4[1]);
      hT[tid * 4 + 2] = bf2f(s4[2]);
      hT[tid * 4 + 3] = bf2f(s4[3]);
    }
    __syncthreads();
    {
      float s = fc_b0[tid];
      const float4* wrow = (const float4*)(fc_w0 + (size_t)tid * HID);
#pragma unroll 4
      for (int k4 = 0; k4 < 128; ++k4) {
        float4 wq = wrow[k4];
        s += hT[4 * k4 + 0] * wq.x + hT[4 * k4 + 1] * wq.y +
             hT[4 * k4 + 2] * wq.z + hT[4 * k4 + 3] * wq.w;
      }
      hfc[tid] = tanhfast(s);
    }
    __syncthreads();
    if (tid < 64) {
#pragma unroll
      for (int kk = 0; kk < 2; ++kk) {
        float p = 0.f;
        for (int j = tid; j < 256; j += 64) p += hfc[j] * fc_w1[kk * 256 + j];
#pragma unroll
        for (int off = 32; off; off >>= 1) p += __shfl_down(p, off, 64);
        if (tid == 0) out[bid * 2 + kk] = p * 0.85f + (fc_b1[kk] * 0.85f + 3.35f);
      }
    }
  }
}

extern "C" void kernel_launch(void* const* d_in, const int* in_sizes, int n_in,
                              void* d_out, int out_size, void* d_ws, size_t ws_size,
                              hipStream_t stream) {
  const float* u_seq  = (const float*)d_in[0];
  const float* w_ih_0 = (const float*)d_in[1];
  const float* w_hh_0 = (const float*)d_in[2];
  const float* b_ih_0 = (const float*)d_in[3];
  const float* b_hh_0 = (const float*)d_in[4];
  const float* w_ih_1 = (const float*)d_in[5];
  const float* w_hh_1 = (const float*)d_in[6];
  const float* b_ih_1 = (const float*)d_in[7];
  const float* b_hh_1 = (const float*)d_in[8];
  const float* fc_w0  = (const float*)d_in[9];
  const float* fc_b0  = (const float*)d_in[10];
  const float* fc_w1  = (const float*)d_in[11];
  const float* fc_b1  = (const float*)d_in[12];
  float* out = (float*)d_out;

  // ws: [0,16KB) 64B-padded flags (0xAA poison is negative -> safe); group
  //     tick counters live at bytes [32,40) of each group-leader flag line
  //     (zeroed in-kernel before the boot barrier);
  //     [16KB, 16KB+1MB) double-buffered h (bf16, 2KB/row)
  int* flags = (int*)d_ws;
  u64* hbuf  = (u64*)((char*)d_ws + 16384);

  size_t shmem = (size_t)NB * L1_RB;  // 66048 B
  hipFuncSetAttribute((const void*)lstm_persist,
                      hipFuncAttributeMaxDynamicSharedMemorySize, (int)shmem);
  hipLaunchKernelGGL(lstm_persist, dim3(256), dim3(256), shmem, stream,
                     u_seq, w_ih_0, w_hh_0, b_ih_0, b_hh_0,
                     w_ih_1, w_hh_1, b_ih_1, b_hh_1,
                     fc_w0, fc_b0, fc_w1, fc_b1, out, flags, hbuf);
}

// Round 6
// 3581.458 us; speedup vs baseline: 1.4919x; 1.4919x over previous
//
#include <hip/hip_runtime.h>
#include <stdint.h>

#define HID   512
#define SEQT  512
#define NB    32            // batches per group
#define L1_RB 2064          // LDS row stride B, layer1: 2048 data + 16 pad
#define L0_RB 1072          // LDS row stride B, layer0: 1024 h0 + 16 u + 16 zeros + 16 pad
#define BUF1_U64 65536      // 256 rows * 256 u64 per h buffer
#define FPAD 16             // flags padded to 64B (16 ints)

typedef __attribute__((ext_vector_type(8)))  __bf16 bf16x8;
typedef __attribute__((ext_vector_type(16))) float  f32x16;
typedef unsigned long long u64;

__device__ __forceinline__ unsigned short f2bf(float x) {
  union { float f; unsigned u; } v; v.f = x;
  return (unsigned short)((v.u + 0x7FFFu + ((v.u >> 16) & 1u)) >> 16);  // RNE
}
__device__ __forceinline__ float bf2f(unsigned short h) {
  union { unsigned u; float f; } v; v.u = ((unsigned)h) << 16;
  return v.f;
}
__device__ __forceinline__ float sigm(float x)     { return 1.0f / (1.0f + __expf(-x)); }
__device__ __forceinline__ float tanhfast(float x) { return 2.0f / (1.0f + __expf(-2.0f * x)) - 1.0f; }

__device__ __forceinline__ u64 ld_agent(const u64* p) {
  return __hip_atomic_load(p, __ATOMIC_RELAXED, __HIP_MEMORY_SCOPE_AGENT);
}
__device__ __forceinline__ void st_agent(u64* p, u64 v) {
  __hip_atomic_store(p, v, __ATOMIC_RELAXED, __HIP_MEMORY_SCOPE_AGENT);
}
// publish h via no-return atomic swap: executes AT the coherence point (line
// stays dirty there) instead of the plain-store write-through path.
__device__ __forceinline__ void swp_agent(u64* p, u64 v) {
  (void)__hip_atomic_exchange(p, v, __ATOMIC_RELAXED, __HIP_MEMORY_SCOPE_AGENT);
}

// async global->LDS DMA, 16B/lane, cpol sc0|sc1 (0x11): bypass L1+L2, read at
// the IF$ coherence point. No VGPR round trip -> fully vmcnt-pipelined.
__device__ __forceinline__ void dma16(const void* g, void* l) {
  __builtin_amdgcn_global_load_lds((const unsigned int*)g, (unsigned int*)l, 16, 0, 0x11);
}

// 256 blocks = 8 groups x 32 (16 layer0 + 16 layer1), 32 batches/group.
// Weights in registers; per tick: DMA-stage group h-tile to LDS, MFMA (dual acc
// chains), lane-local cell update, h publish, 1 padded-flag barrier per tick.
// Barrier mechanism = proven round-0 (own-line store + 32-lane scan + s_sleep).
// NEW: layer-split thresholds. L0's only dependency on L1 is WAR (L1 finished
// READING the buffer L0 overwrites) = one tick of slack -> L0 polls L1 at
// gen-1. L1 keeps full gen on both (h0 is a true data edge). L0 runs ~1 tick
// ahead; the critical chain narrows to L1's 16-block all-gather.
__global__ __launch_bounds__(256, 1) void lstm_persist(
    const float* __restrict__ u_seq,
    const float* __restrict__ w_ih_0, const float* __restrict__ w_hh_0,
    const float* __restrict__ b_ih_0, const float* __restrict__ b_hh_0,
    const float* __restrict__ w_ih_1, const float* __restrict__ w_hh_1,
    const float* __restrict__ b_ih_1, const float* __restrict__ b_hh_1,
    const float* __restrict__ fc_w0, const float* __restrict__ fc_b0,
    const float* __restrict__ fc_w1, const float* __restrict__ fc_b1,
    float* __restrict__ out, int* flags, u64* hbuf)
{
  extern __shared__ char smemc[];    // B-tile staging (66048 B for L1 blocks)

  const int bid  = blockIdx.x;
  const int g    = bid >> 5;            // group 0..7
  const int rr   = bid & 31;            // rank in group
  const int isL1 = rr >> 4;
  const int rl   = rr & 15;             // rank within layer
  const int tid  = threadIdx.x;
  const int wv   = tid >> 6;
  const int lane = tid & 63;
  const int lcol = lane & 31;           // A row (gate row) / B col (batch)
  const int kh   = lane >> 5;           // K-half within MFMA step
  const int batch0 = g * NB;

  const int unit_base = rl * 32 + wv * 8;       // 8 units per wave
  const int prow = unit_base * 4 + lcol;        // permuted gate row (4u+gate)
  const int orig = (prow & 3) * HID + (prow >> 2);

  // L0 blocks poll L1 flags (ranks 16..31, scanned by lanes 16..31) at gen-1
  // (WAR-only edge); everything else at gen. Poisoned flags are negative.
  const int mylag = (!isL1 && tid >= 16 && tid < 32) ? 1 : 0;

  auto groupbar = [&](int gen) {
    __syncthreads();   // drains vmcnt (h publishes acked at IF$) before flag store
    if (tid == 0)
      __hip_atomic_store(&flags[bid * FPAD], gen, __ATOMIC_RELAXED, __HIP_MEMORY_SCOPE_AGENT);
    if (tid < 32) {
      const int* fl = flags + (g * 32 + tid) * FPAD;
      const int thr = gen - mylag;
      while (__hip_atomic_load(fl, __ATOMIC_RELAXED, __HIP_MEMORY_SCOPE_AGENT) < thr)
        __builtin_amdgcn_s_sleep(1);
    }
    __syncthreads();
  };

  // ---- zero both h buffers (ws poisoned 0xAA) ----
  {
    u64* p = hbuf + (size_t)bid * 512;
    st_agent(p + tid, 0);
    st_agent(p + tid + 256, 0);
  }
  int gen = 1;
  groupbar(gen++);

  if (isL1) {
    // ================= LAYER 1 BLOCK =================
    bf16x8 w[64];   // A-frags resident: 256 regs (unified VGPR/AGPR file, 1 wave/SIMD)
    {
      const float* bih = w_ih_1 + (size_t)orig * HID;   // k<512: input = h0
      const float* bhh = w_hh_1 + (size_t)orig * HID;   // k>=512: recurrent h1
#pragma unroll
      for (int s = 0; s < 64; ++s) {
        int k = s * 16 + kh * 8;
        const float* src = (k < HID) ? (bih + k) : (bhh + (k - HID));
        float4 f0 = *(const float4*)src, f1 = *(const float4*)(src + 4);
        union { bf16x8 v; unsigned short h[8]; } u;
        u.h[0]=f2bf(f0.x); u.h[1]=f2bf(f0.y); u.h[2]=f2bf(f0.z); u.h[3]=f2bf(f0.w);
        u.h[4]=f2bf(f1.x); u.h[5]=f2bf(f1.y); u.h[6]=f2bf(f1.z); u.h[7]=f2bf(f1.w);
        w[s] = u.v;
      }
    }
    float bias[16];
#pragma unroll
    for (int rg = 0; rg < 16; ++rg) {
      int unit = unit_base + 2 * (rg >> 2) + kh;
      int gi = (rg & 3) * HID + unit;
      bias[rg] = b_ih_1[gi] + b_hh_1[gi];
    }
    float cc[4] = {0.f, 0.f, 0.f, 0.f};

    for (int tau = 0; tau <= SEQT; ++tau) {
      const char* curb = (const char*)(hbuf + ((tau & 1) ? BUF1_U64 : 0));
      u64*        nxt  = hbuf + ((tau & 1) ? 0 : BUF1_U64);
      if (tau >= 1) {
        // DMA-stage 32 rows x 2KB; wave wv handles rows wv*8..wv*8+7.
        // Chunk-1 (row bytes [0,1024) = MFMA s 0..31) issued FIRST so
        // vmcnt(8) certifies it while chunk-2 is still in flight.
#pragma unroll
        for (int j = 0; j < 8; ++j) {
          int b = wv * 8 + j;
          const char* gr = curb + ((size_t)(batch0 + b) << 11) + lane * 16;
          dma16(gr, smemc + b * L1_RB);
        }
#pragma unroll
        for (int j = 0; j < 8; ++j) {
          int b = wv * 8 + j;
          const char* gr = curb + ((size_t)(batch0 + b) << 11) + 1024 + lane * 16;
          dma16(gr, smemc + b * L1_RB + 1024);
        }
        f32x16 a0, a1;
#pragma unroll
        for (int i = 0; i < 16; ++i) { a0[i] = bias[i]; a1[i] = 0.f; }
        const char* brow = smemc + lcol * L1_RB + kh * 16;
        // phase 1: chunk-1 landed for all waves (own vmcnt(8) + barrier)
        asm volatile("s_waitcnt vmcnt(8)" ::: "memory");
        __builtin_amdgcn_s_barrier();
        asm volatile("" ::: "memory");
#pragma unroll
        for (int s = 0; s < 32; s += 2) {
          bf16x8 b0 = *(const bf16x8*)(brow + s * 32);
          bf16x8 b1 = *(const bf16x8*)(brow + s * 32 + 32);
          a0 = __builtin_amdgcn_mfma_f32_32x32x16_bf16(w[s],     b0, a0, 0, 0, 0);
          a1 = __builtin_amdgcn_mfma_f32_32x32x16_bf16(w[s + 1], b1, a1, 0, 0, 0);
        }
        // phase 2: chunk-2 landed (vmcnt(0) + barrier)
        asm volatile("s_waitcnt vmcnt(0)" ::: "memory");
        __builtin_amdgcn_s_barrier();
        asm volatile("" ::: "memory");
#pragma unroll
        for (int s = 32; s < 64; s += 2) {
          bf16x8 b0 = *(const bf16x8*)(brow + s * 32);
          bf16x8 b1 = *(const bf16x8*)(brow + s * 32 + 32);
          a0 = __builtin_amdgcn_mfma_f32_32x32x16_bf16(w[s],     b0, a0, 0, 0, 0);
          a1 = __builtin_amdgcn_mfma_f32_32x32x16_bf16(w[s + 1], b1, a1, 0, 0, 0);
        }
        float hv[4];
#pragma unroll
        for (int q = 0; q < 4; ++q) {
          float ig = sigm(a0[4 * q + 0] + a1[4 * q + 0]);
          float fg = sigm(a0[4 * q + 1] + a1[4 * q + 1]);
          float gg = tanhfast(a0[4 * q + 2] + a1[4 * q + 2]);
          float og = sigm(a0[4 * q + 3] + a1[4 * q + 3]);
          float c = fg * cc[q] + ig * gg;
          cc[q] = c;
          hv[q] = og * tanhfast(c);
        }
        unsigned own01 = (unsigned)f2bf(hv[0]) | ((unsigned)f2bf(hv[1]) << 16);
        unsigned own23 = (unsigned)f2bf(hv[2]) | ((unsigned)f2bf(hv[3]) << 16);
        unsigned p01 = (unsigned)__shfl_xor((int)own01, 32);
        unsigned p23 = (unsigned)__shfl_xor((int)own23, 32);
        if (kh == 0) {   // interleave even(own)/odd(partner) units -> 16B contiguous
          u64 q0 = ((u64)((own01 & 0xffffu) | ((p01 & 0xffffu) << 16)))
                 | (((u64)((own01 >> 16) | (p01 & 0xffff0000u))) << 32);
          u64 q1 = ((u64)((own23 & 0xffffu) | ((p23 & 0xffffu) << 16)))
                 | (((u64)((own23 >> 16) | (p23 & 0xffff0000u))) << 32);
          u64* orow = nxt + (size_t)(batch0 + lcol) * 256 + 128 + (unit_base >> 2);
          swp_agent(orow, q0);
          swp_agent(orow + 1, q1);
        }
      }
      groupbar(gen++);
    }
  } else {
    // ================= LAYER 0 BLOCK =================
    bf16x8 w[33];
    {
      const float* bhh = w_hh_0 + (size_t)orig * HID;
#pragma unroll
      for (int s = 0; s < 32; ++s) {
        int k = s * 16 + kh * 8;
        float4 f0 = *(const float4*)(bhh + k), f1 = *(const float4*)(bhh + k + 4);
        union { bf16x8 v; unsigned short h[8]; } u;
        u.h[0]=f2bf(f0.x); u.h[1]=f2bf(f0.y); u.h[2]=f2bf(f0.z); u.h[3]=f2bf(f0.w);
        u.h[4]=f2bf(f1.x); u.h[5]=f2bf(f1.y); u.h[6]=f2bf(f1.z); u.h[7]=f2bf(f1.w);
        w[s] = u.v;
      }
      { // step 32: kh=0 -> u columns, kh=1 -> zeros (row pad region)
        union { bf16x8 v; unsigned short h[8]; } u;
        if (kh == 0) {
          const float* src = w_ih_0 + (size_t)orig * 8;
#pragma unroll
          for (int j = 0; j < 8; ++j) u.h[j] = f2bf(src[j]);
        } else {
#pragma unroll
          for (int j = 0; j < 8; ++j) u.h[j] = 0;
        }
        w[32] = u.v;
      }
    }
    float bias[16];
#pragma unroll
    for (int rg = 0; rg < 16; ++rg) {
      int unit = unit_base + 2 * (rg >> 2) + kh;
      int gi = (rg & 3) * HID + unit;
      bias[rg] = b_ih_0[gi] + b_hh_0[gi];
    }
    float cc[4] = {0.f, 0.f, 0.f, 0.f};

    // zeros for kh=1 of MFMA step 32: row bytes [1040,1056), written once
    if (tid < 64) *(u64*)(smemc + (tid >> 1) * L0_RB + 1040 + (tid & 1) * 8) = 0;

    // u prefetch: thread tid stages element (batch b, col i) each tick
    const int ub = tid >> 3, ui = tid & 7;
    const float* usrc = u_seq + (size_t)(batch0 + ub) * SEQT * 8 + ui;
    float unext = usrc[0];   // u(0); overlaps boot barrier

    for (int tau = 0; tau <= SEQT; ++tau) {
      const char* curb = (const char*)(hbuf + ((tau & 1) ? BUF1_U64 : 0));
      u64*        nxt  = hbuf + ((tau & 1) ? 0 : BUF1_U64);
      if (tau < SEQT) {
#pragma unroll
        for (int j = 0; j < 8; ++j) {
          int b = wv * 8 + j;
          const char* gr = curb + ((size_t)(batch0 + b) << 11) + lane * 16;
          dma16(gr, smemc + b * L0_RB);   // h0 half only (1KB)
        }
        // stage u_tau (prefetched last tick) into row bytes [1024,1040)
        ((unsigned short*)(smemc + ub * L0_RB))[512 + ui] = f2bf(unext);
        __syncthreads();
        f32x16 a0, a1;
#pragma unroll
        for (int i = 0; i < 16; ++i) { a0[i] = bias[i]; a1[i] = 0.f; }
        const char* brow = smemc + lcol * L0_RB + kh * 16;
#pragma unroll
        for (int s = 0; s < 32; s += 2) {
          bf16x8 b0 = *(const bf16x8*)(brow + s * 32);
          bf16x8 b1 = *(const bf16x8*)(brow + s * 32 + 32);
          a0 = __builtin_amdgcn_mfma_f32_32x32x16_bf16(w[s],     b0, a0, 0, 0, 0);
          a1 = __builtin_amdgcn_mfma_f32_32x32x16_bf16(w[s + 1], b1, a1, 0, 0, 0);
        }
        { // step 32: u fold (kh=0) / zeros (kh=1) at row offset 32*32
          bf16x8 b2 = *(const bf16x8*)(brow + 32 * 32);
          a0 = __builtin_amdgcn_mfma_f32_32x32x16_bf16(w[32], b2, a0, 0, 0, 0);
        }
        // prefetch u(tau+1): latency hides under update + barrier
        if (tau + 1 < SEQT) unext = usrc[(size_t)(tau + 1) * 8];
        float hv[4];
#pragma unroll
        for (int q = 0; q < 4; ++q) {
          float ig = sigm(a0[4 * q + 0] + a1[4 * q + 0]);
          float fg = sigm(a0[4 * q + 1] + a1[4 * q + 1]);
          float gg = tanhfast(a0[4 * q + 2] + a1[4 * q + 2]);
          float og = sigm(a0[4 * q + 3] + a1[4 * q + 3]);
          float c = fg * cc[q] + ig * gg;
          cc[q] = c;
          hv[q] = og * tanhfast(c);
        }
        unsigned own01 = (unsigned)f2bf(hv[0]) | ((unsigned)f2bf(hv[1]) << 16);
        unsigned own23 = (unsigned)f2bf(hv[2]) | ((unsigned)f2bf(hv[3]) << 16);
        unsigned p01 = (unsigned)__shfl_xor((int)own01, 32);
        unsigned p23 = (unsigned)__shfl_xor((int)own23, 32);
        if (kh == 0) {
          u64 q0 = ((u64)((own01 & 0xffffu) | ((p01 & 0xffffu) << 16)))
                 | (((u64)((own01 >> 16) | (p01 & 0xffff0000u))) << 32);
          u64 q1 = ((u64)((own23 & 0xffffu) | ((p23 & 0xffffu) << 16)))
                 | (((u64)((own23 >> 16) | (p23 & 0xffff0000u))) << 32);
          u64* orow = nxt + (size_t)(batch0 + lcol) * 256 + (unit_base >> 2);
          swp_agent(orow, q0);
          swp_agent(orow + 1, q1);
        }
      }
      groupbar(gen++);
    }
    // L0's relaxed L1-threshold doesn't guarantee L1 finished tick SEQT;
    // FC reads h1(T-1) written then -> explicit wait for L1 final flags.
    if (tid < 16) {
      const int* fl = flags + (g * 32 + 16 + tid) * FPAD;
      while (__hip_atomic_load(fl, __ATOMIC_RELAXED, __HIP_MEMORY_SCOPE_AGENT) < SEQT + 2)
        __builtin_amdgcn_s_sleep(1);
    }
    __syncthreads();
  }

  // ---- FC head (fp32): block bid handles batch bid ----
  {
    float* hT  = (float*)smemc;          // [512]
    float* hfc = ((float*)smemc) + 512;  // [256]
    const u64* hrow = hbuf + BUF1_U64 + (size_t)bid * 256 + 128;  // h1_{T-1} in buf1
    if (tid < 128) {
      u64 v = ld_agent(hrow + tid);
      const unsigned short* s4 = (const unsigned short*)&v;
      hT[tid * 4 + 0] = bf2f(s4[0]);
      hT[tid * 4 + 1] = bf2f(s4[1]);
      hT[tid * 4 + 2] = bf2f(s4[2]);
      hT[tid * 4 + 3] = bf2f(s4[3]);
    }
    __syncthreads();
    {
      float s = fc_b0[tid];
      const float4* wrow = (const float4*)(fc_w0 + (size_t)tid * HID);
#pragma unroll 4
      for (int k4 = 0; k4 < 128; ++k4) {
        float4 wq = wrow[k4];
        s += hT[4 * k4 + 0] * wq.x + hT[4 * k4 + 1] * wq.y +
             hT[4 * k4 + 2] * wq.z + hT[4 * k4 + 3] * wq.w;
      }
      hfc[tid] = tanhfast(s);
    }
    __syncthreads();
    if (tid < 64) {
#pragma unroll
      for (int kk = 0; kk < 2; ++kk) {
        float p = 0.f;
        for (int j = tid; j < 256; j += 64) p += hfc[j] * fc_w1[kk * 256 + j];
#pragma unroll
        for (int off = 32; off; off >>= 1) p += __shfl_down(p, off, 64);
        if (tid == 0) out[bid * 2 + kk] = p * 0.85f + (fc_b1[kk] * 0.85f + 3.35f);
      }
    }
  }
}

extern "C" void kernel_launch(void* const* d_in, const int* in_sizes, int n_in,
                              void* d_out, int out_size, void* d_ws, size_t ws_size,
                              hipStream_t stream) {
  const float* u_seq  = (const float*)d_in[0];
  const float* w_ih_0 = (const float*)d_in[1];
  const float* w_hh_0 = (const float*)d_in[2];
  const float* b_ih_0 = (const float*)d_in[3];
  const float* b_hh_0 = (const float*)d_in[4];
  const float* w_ih_1 = (const float*)d_in[5];
  const float* w_hh_1 = (const float*)d_in[6];
  const float* b_ih_1 = (const float*)d_in[7];
  const float* b_hh_1 = (const float*)d_in[8];
  const float* fc_w0  = (const float*)d_in[9];
  const float* fc_b0  = (const float*)d_in[10];
  const float* fc_w1  = (const float*)d_in[11];
  const float* fc_b1  = (const float*)d_in[12];
  float* out = (float*)d_out;

  // ws: [0,16KB) 64B-padded flags (0xAA poison is negative -> safe);
  //     [16KB, 16KB+1MB) double-buffered h (bf16, 2KB/row)
  int* flags = (int*)d_ws;
  u64* hbuf  = (u64*)((char*)d_ws + 16384);

  size_t shmem = (size_t)NB * L1_RB;  // 66048 B
  hipFuncSetAttribute((const void*)lstm_persist,
                      hipFuncAttributeMaxDynamicSharedMemorySize, (int)shmem);
  hipLaunchKernelGGL(lstm_persist, dim3(256), dim3(256), shmem, stream,
                     u_seq, w_ih_0, w_hh_0, b_ih_0, b_hh_0,
                     w_ih_1, w_hh_1, b_ih_1, b_hh_1,
                     fc_w0, fc_b0, fc_w1, fc_b1, out, flags, hbuf);
}

// Round 7
// 2480.906 us; speedup vs baseline: 2.1537x; 1.4436x over previous
//
#include <hip/hip_runtime.h>
#include <stdint.h>

#define HID   512
#define SEQT  512
#define NB    32            // batches per group
#define L1_RB 2064          // LDS row stride B, layer1: 2048 data + 16 pad
#define L0_RB 1072          // LDS row stride B, layer0: 1024 h0 + 16 u + 16 zeros + 16 pad
#define BUF1_U64 65536      // 256 rows * 256 u64 per h buffer
#define FPAD 16             // flags padded to 64B (16 ints)

typedef __attribute__((ext_vector_type(8)))  __bf16 bf16x8;
typedef __attribute__((ext_vector_type(16))) float  f32x16;
typedef unsigned long long u64;

__device__ __forceinline__ unsigned short f2bf(float x) {
  union { float f; unsigned u; } v; v.f = x;
  return (unsigned short)((v.u + 0x7FFFu + ((v.u >> 16) & 1u)) >> 16);  // RNE
}
__device__ __forceinline__ float bf2f(unsigned short h) {
  union { unsigned u; float f; } v; v.u = ((unsigned)h) << 16;
  return v.f;
}
__device__ __forceinline__ float sigm(float x)     { return 1.0f / (1.0f + __expf(-x)); }
__device__ __forceinline__ float tanhfast(float x) { return 2.0f / (1.0f + __expf(-2.0f * x)) - 1.0f; }

__device__ __forceinline__ u64 ld_agent(const u64* p) {
  return __hip_atomic_load(p, __ATOMIC_RELAXED, __HIP_MEMORY_SCOPE_AGENT);
}
__device__ __forceinline__ void st_agent(u64* p, u64 v) {
  __hip_atomic_store(p, v, __ATOMIC_RELAXED, __HIP_MEMORY_SCOPE_AGENT);
}

// async global->LDS DMA, 16B/lane, cpol sc0|sc1 (0x11): bypass L1+L2, read at
// the IF$ coherence point. No VGPR round trip -> fully vmcnt-pipelined.
__device__ __forceinline__ void dma16(const void* g, void* l) {
  __builtin_amdgcn_global_load_lds((const unsigned int*)g, (unsigned int*)l, 16, 0, 0x11);
}

// 256 blocks = 8 groups x 32 (16 layer0 + 16 layer1), 32 batches/group.
// Weights in registers; per tick: DMA-stage group h-tile to LDS, MFMA (dual acc
// chains), lane-local cell update, sc1 h-store, 1 padded-flag barrier per tick.
// Publish path = plain agent-scope stores (proven; atomics regress 1.4-2x).
// Layer-split thresholds: L0's only dependency on L1 is WAR (L1 finished
// READING the buffer L0 overwrites) = one tick of slack -> L0 polls L1 at
// gen-1. L1 keeps full gen on both (h0 is a true data edge). L0 runs ~1 tick
// ahead; the critical chain narrows to L1's 16-block all-gather.
__global__ __launch_bounds__(256, 1) void lstm_persist(
    const float* __restrict__ u_seq,
    const float* __restrict__ w_ih_0, const float* __restrict__ w_hh_0,
    const float* __restrict__ b_ih_0, const float* __restrict__ b_hh_0,
    const float* __restrict__ w_ih_1, const float* __restrict__ w_hh_1,
    const float* __restrict__ b_ih_1, const float* __restrict__ b_hh_1,
    const float* __restrict__ fc_w0, const float* __restrict__ fc_b0,
    const float* __restrict__ fc_w1, const float* __restrict__ fc_b1,
    float* __restrict__ out, int* flags, u64* hbuf)
{
  extern __shared__ char smemc[];    // B-tile staging (66048 B for L1 blocks)

  const int bid  = blockIdx.x;
  const int g    = bid >> 5;            // group 0..7
  const int rr   = bid & 31;            // rank in group
  const int isL1 = rr >> 4;
  const int rl   = rr & 15;             // rank within layer
  const int tid  = threadIdx.x;
  const int wv   = tid >> 6;
  const int lane = tid & 63;
  const int lcol = lane & 31;           // A row (gate row) / B col (batch)
  const int kh   = lane >> 5;           // K-half within MFMA step
  const int batch0 = g * NB;

  const int unit_base = rl * 32 + wv * 8;       // 8 units per wave
  const int prow = unit_base * 4 + lcol;        // permuted gate row (4u+gate)
  const int orig = (prow & 3) * HID + (prow >> 2);

  // L0 blocks poll L1 flags (ranks 16..31, scanned by lanes 16..31) at gen-1
  // (WAR-only edge); everything else at gen. Poisoned flags are negative, so
  // thr=0 at boot still blocks until the real gen=1 store lands.
  const int mylag = (!isL1 && tid >= 16 && tid < 32) ? 1 : 0;

  auto groupbar = [&](int gen) {
    __syncthreads();   // drains vmcnt (h-stores acked at IF$) before flag store
    if (tid == 0)
      __hip_atomic_store(&flags[bid * FPAD], gen, __ATOMIC_RELAXED, __HIP_MEMORY_SCOPE_AGENT);
    if (tid < 32) {
      const int* fl = flags + (g * 32 + tid) * FPAD;
      const int thr = gen - mylag;
      while (__hip_atomic_load(fl, __ATOMIC_RELAXED, __HIP_MEMORY_SCOPE_AGENT) < thr)
        __builtin_amdgcn_s_sleep(1);
    }
    __syncthreads();
  };

  // ---- zero both h buffers (ws poisoned 0xAA) ----
  {
    u64* p = hbuf + (size_t)bid * 512;
    st_agent(p + tid, 0);
    st_agent(p + tid + 256, 0);
  }
  int gen = 1;
  groupbar(gen++);

  if (isL1) {
    // ================= LAYER 1 BLOCK =================
    bf16x8 w[64];   // A-frags resident: 256 regs (unified VGPR/AGPR file, 1 wave/SIMD)
    {
      const float* bih = w_ih_1 + (size_t)orig * HID;   // k<512: input = h0
      const float* bhh = w_hh_1 + (size_t)orig * HID;   // k>=512: recurrent h1
#pragma unroll
      for (int s = 0; s < 64; ++s) {
        int k = s * 16 + kh * 8;
        const float* src = (k < HID) ? (bih + k) : (bhh + (k - HID));
        float4 f0 = *(const float4*)src, f1 = *(const float4*)(src + 4);
        union { bf16x8 v; unsigned short h[8]; } u;
        u.h[0]=f2bf(f0.x); u.h[1]=f2bf(f0.y); u.h[2]=f2bf(f0.z); u.h[3]=f2bf(f0.w);
        u.h[4]=f2bf(f1.x); u.h[5]=f2bf(f1.y); u.h[6]=f2bf(f1.z); u.h[7]=f2bf(f1.w);
        w[s] = u.v;
      }
    }
    float bias[16];
#pragma unroll
    for (int rg = 0; rg < 16; ++rg) {
      int unit = unit_base + 2 * (rg >> 2) + kh;
      int gi = (rg & 3) * HID + unit;
      bias[rg] = b_ih_1[gi] + b_hh_1[gi];
    }
    float cc[4] = {0.f, 0.f, 0.f, 0.f};

    for (int tau = 0; tau <= SEQT; ++tau) {
      const char* curb = (const char*)(hbuf + ((tau & 1) ? BUF1_U64 : 0));
      u64*        nxt  = hbuf + ((tau & 1) ? 0 : BUF1_U64);
      if (tau >= 1) {
        // DMA-stage 32 rows x 2KB; wave wv handles rows wv*8..wv*8+7.
        // Chunk-1 (row bytes [0,1024) = MFMA s 0..31) issued FIRST so
        // vmcnt(8) certifies it while chunk-2 is still in flight.
#pragma unroll
        for (int j = 0; j < 8; ++j) {
          int b = wv * 8 + j;
          const char* gr = curb + ((size_t)(batch0 + b) << 11) + lane * 16;
          dma16(gr, smemc + b * L1_RB);
        }
#pragma unroll
        for (int j = 0; j < 8; ++j) {
          int b = wv * 8 + j;
          const char* gr = curb + ((size_t)(batch0 + b) << 11) + 1024 + lane * 16;
          dma16(gr, smemc + b * L1_RB + 1024);
        }
        f32x16 a0, a1;
#pragma unroll
        for (int i = 0; i < 16; ++i) { a0[i] = bias[i]; a1[i] = 0.f; }
        const char* brow = smemc + lcol * L1_RB + kh * 16;
        // phase 1: chunk-1 landed for all waves (own vmcnt(8) + barrier)
        asm volatile("s_waitcnt vmcnt(8)" ::: "memory");
        __builtin_amdgcn_s_barrier();
        asm volatile("" ::: "memory");
#pragma unroll
        for (int s = 0; s < 32; s += 2) {
          bf16x8 b0 = *(const bf16x8*)(brow + s * 32);
          bf16x8 b1 = *(const bf16x8*)(brow + s * 32 + 32);
          a0 = __builtin_amdgcn_mfma_f32_32x32x16_bf16(w[s],     b0, a0, 0, 0, 0);
          a1 = __builtin_amdgcn_mfma_f32_32x32x16_bf16(w[s + 1], b1, a1, 0, 0, 0);
        }
        // phase 2: chunk-2 landed (vmcnt(0) + barrier)
        asm volatile("s_waitcnt vmcnt(0)" ::: "memory");
        __builtin_amdgcn_s_barrier();
        asm volatile("" ::: "memory");
#pragma unroll
        for (int s = 32; s < 64; s += 2) {
          bf16x8 b0 = *(const bf16x8*)(brow + s * 32);
          bf16x8 b1 = *(const bf16x8*)(brow + s * 32 + 32);
          a0 = __builtin_amdgcn_mfma_f32_32x32x16_bf16(w[s],     b0, a0, 0, 0, 0);
          a1 = __builtin_amdgcn_mfma_f32_32x32x16_bf16(w[s + 1], b1, a1, 0, 0, 0);
        }
        float hv[4];
#pragma unroll
        for (int q = 0; q < 4; ++q) {
          float ig = sigm(a0[4 * q + 0] + a1[4 * q + 0]);
          float fg = sigm(a0[4 * q + 1] + a1[4 * q + 1]);
          float gg = tanhfast(a0[4 * q + 2] + a1[4 * q + 2]);
          float og = sigm(a0[4 * q + 3] + a1[4 * q + 3]);
          float c = fg * cc[q] + ig * gg;
          cc[q] = c;
          hv[q] = og * tanhfast(c);
        }
        unsigned own01 = (unsigned)f2bf(hv[0]) | ((unsigned)f2bf(hv[1]) << 16);
        unsigned own23 = (unsigned)f2bf(hv[2]) | ((unsigned)f2bf(hv[3]) << 16);
        unsigned p01 = (unsigned)__shfl_xor((int)own01, 32);
        unsigned p23 = (unsigned)__shfl_xor((int)own23, 32);
        if (kh == 0) {   // interleave even(own)/odd(partner) units -> 16B contiguous
          u64 q0 = ((u64)((own01 & 0xffffu) | ((p01 & 0xffffu) << 16)))
                 | (((u64)((own01 >> 16) | (p01 & 0xffff0000u))) << 32);
          u64 q1 = ((u64)((own23 & 0xffffu) | ((p23 & 0xffffu) << 16)))
                 | (((u64)((own23 >> 16) | (p23 & 0xffff0000u))) << 32);
          u64* orow = nxt + (size_t)(batch0 + lcol) * 256 + 128 + (unit_base >> 2);
          st_agent(orow, q0);
          st_agent(orow + 1, q1);
        }
      }
      groupbar(gen++);
    }
  } else {
    // ================= LAYER 0 BLOCK =================
    bf16x8 w[33];
    {
      const float* bhh = w_hh_0 + (size_t)orig * HID;
#pragma unroll
      for (int s = 0; s < 32; ++s) {
        int k = s * 16 + kh * 8;
        float4 f0 = *(const float4*)(bhh + k), f1 = *(const float4*)(bhh + k + 4);
        union { bf16x8 v; unsigned short h[8]; } u;
        u.h[0]=f2bf(f0.x); u.h[1]=f2bf(f0.y); u.h[2]=f2bf(f0.z); u.h[3]=f2bf(f0.w);
        u.h[4]=f2bf(f1.x); u.h[5]=f2bf(f1.y); u.h[6]=f2bf(f1.z); u.h[7]=f2bf(f1.w);
        w[s] = u.v;
      }
      { // step 32: kh=0 -> u columns, kh=1 -> zeros (row pad region)
        union { bf16x8 v; unsigned short h[8]; } u;
        if (kh == 0) {
          const float* src = w_ih_0 + (size_t)orig * 8;
#pragma unroll
          for (int j = 0; j < 8; ++j) u.h[j] = f2bf(src[j]);
        } else {
#pragma unroll
          for (int j = 0; j < 8; ++j) u.h[j] = 0;
        }
        w[32] = u.v;
      }
    }
    float bias[16];
#pragma unroll
    for (int rg = 0; rg < 16; ++rg) {
      int unit = unit_base + 2 * (rg >> 2) + kh;
      int gi = (rg & 3) * HID + unit;
      bias[rg] = b_ih_0[gi] + b_hh_0[gi];
    }
    float cc[4] = {0.f, 0.f, 0.f, 0.f};

    // zeros for kh=1 of MFMA step 32: row bytes [1040,1056), written once
    if (tid < 64) *(u64*)(smemc + (tid >> 1) * L0_RB + 1040 + (tid & 1) * 8) = 0;

    // u prefetch: thread tid stages element (batch b, col i) each tick
    const int ub = tid >> 3, ui = tid & 7;
    const float* usrc = u_seq + (size_t)(batch0 + ub) * SEQT * 8 + ui;
    float unext = usrc[0];   // u(0); overlaps boot barrier

    for (int tau = 0; tau <= SEQT; ++tau) {
      const char* curb = (const char*)(hbuf + ((tau & 1) ? BUF1_U64 : 0));
      u64*        nxt  = hbuf + ((tau & 1) ? 0 : BUF1_U64);
      if (tau < SEQT) {
#pragma unroll
        for (int j = 0; j < 8; ++j) {
          int b = wv * 8 + j;
          const char* gr = curb + ((size_t)(batch0 + b) << 11) + lane * 16;
          dma16(gr, smemc + b * L0_RB);   // h0 half only (1KB)
        }
        // stage u_tau (prefetched last tick) into row bytes [1024,1040)
        ((unsigned short*)(smemc + ub * L0_RB))[512 + ui] = f2bf(unext);
        __syncthreads();
        f32x16 a0, a1;
#pragma unroll
        for (int i = 0; i < 16; ++i) { a0[i] = bias[i]; a1[i] = 0.f; }
        const char* brow = smemc + lcol * L0_RB + kh * 16;
#pragma unroll
        for (int s = 0; s < 32; s += 2) {
          bf16x8 b0 = *(const bf16x8*)(brow + s * 32);
          bf16x8 b1 = *(const bf16x8*)(brow + s * 32 + 32);
          a0 = __builtin_amdgcn_mfma_f32_32x32x16_bf16(w[s],     b0, a0, 0, 0, 0);
          a1 = __builtin_amdgcn_mfma_f32_32x32x16_bf16(w[s + 1], b1, a1, 0, 0, 0);
        }
        { // step 32: u fold (kh=0) / zeros (kh=1) at row offset 32*32
          bf16x8 b2 = *(const bf16x8*)(brow + 32 * 32);
          a0 = __builtin_amdgcn_mfma_f32_32x32x16_bf16(w[32], b2, a0, 0, 0, 0);
        }
        // prefetch u(tau+1): latency hides under update + barrier
        if (tau + 1 < SEQT) unext = usrc[(size_t)(tau + 1) * 8];
        float hv[4];
#pragma unroll
        for (int q = 0; q < 4; ++q) {
          float ig = sigm(a0[4 * q + 0] + a1[4 * q + 0]);
          float fg = sigm(a0[4 * q + 1] + a1[4 * q + 1]);
          float gg = tanhfast(a0[4 * q + 2] + a1[4 * q + 2]);
          float og = sigm(a0[4 * q + 3] + a1[4 * q + 3]);
          float c = fg * cc[q] + ig * gg;
          cc[q] = c;
          hv[q] = og * tanhfast(c);
        }
        unsigned own01 = (unsigned)f2bf(hv[0]) | ((unsigned)f2bf(hv[1]) << 16);
        unsigned own23 = (unsigned)f2bf(hv[2]) | ((unsigned)f2bf(hv[3]) << 16);
        unsigned p01 = (unsigned)__shfl_xor((int)own01, 32);
        unsigned p23 = (unsigned)__shfl_xor((int)own23, 32);
        if (kh == 0) {
          u64 q0 = ((u64)((own01 & 0xffffu) | ((p01 & 0xffffu) << 16)))
                 | (((u64)((own01 >> 16) | (p01 & 0xffff0000u))) << 32);
          u64 q1 = ((u64)((own23 & 0xffffu) | ((p23 & 0xffffu) << 16)))
                 | (((u64)((own23 >> 16) | (p23 & 0xffff0000u))) << 32);
          u64* orow = nxt + (size_t)(batch0 + lcol) * 256 + (unit_base >> 2);
          st_agent(orow, q0);
          st_agent(orow + 1, q1);
        }
      }
      groupbar(gen++);
    }
    // L0's relaxed L1-threshold doesn't guarantee L1 finished tick SEQT;
    // FC reads h1(T-1) written then -> explicit wait for L1 final flags.
    if (tid < 16) {
      const int* fl = flags + (g * 32 + 16 + tid) * FPAD;
      while (__hip_atomic_load(fl, __ATOMIC_RELAXED, __HIP_MEMORY_SCOPE_AGENT) < SEQT + 2)
        __builtin_amdgcn_s_sleep(1);
    }
    __syncthreads();
  }

  // ---- FC head (fp32): block bid handles batch bid ----
  {
    float* hT  = (float*)smemc;          // [512]
    float* hfc = ((float*)smemc) + 512;  // [256]
    const u64* hrow = hbuf + BUF1_U64 + (size_t)bid * 256 + 128;  // h1_{T-1} in buf1
    if (tid < 128) {
      u64 v = ld_agent(hrow + tid);
      const unsigned short* s4 = (const unsigned short*)&v;
      hT[tid * 4 + 0] = bf2f(s4[0]);
      hT[tid * 4 + 1] = bf2f(s4[1]);
      hT[tid * 4 + 2] = bf2f(s4[2]);
      hT[tid * 4 + 3] = bf2f(s4[3]);
    }
    __syncthreads();
    {
      float s = fc_b0[tid];
      const float4* wrow = (const float4*)(fc_w0 + (size_t)tid * HID);
#pragma unroll 4
      for (int k4 = 0; k4 < 128; ++k4) {
        float4 wq = wrow[k4];
        s += hT[4 * k4 + 0] * wq.x + hT[4 * k4 + 1] * wq.y +
             hT[4 * k4 + 2] * wq.z + hT[4 * k4 + 3] * wq.w;
      }
      hfc[tid] = tanhfast(s);
    }
    __syncthreads();
    if (tid < 64) {
#pragma unroll
      for (int kk = 0; kk < 2; ++kk) {
        float p = 0.f;
        for (int j = tid; j < 256; j += 64) p += hfc[j] * fc_w1[kk * 256 + j];
#pragma unroll
        for (int off = 32; off; off >>= 1) p += __shfl_down(p, off, 64);
        if (tid == 0) out[bid * 2 + kk] = p * 0.85f + (fc_b1[kk] * 0.85f + 3.35f);
      }
    }
  }
}

extern "C" void kernel_launch(void* const* d_in, const int* in_sizes, int n_in,
                              void* d_out, int out_size, void* d_ws, size_t ws_size,
                              hipStream_t stream) {
  const float* u_seq  = (const float*)d_in[0];
  const float* w_ih_0 = (const float*)d_in[1];
  const float* w_hh_0 = (const float*)d_in[2];
  const float* b_ih_0 = (const float*)d_in[3];
  const float* b_hh_0 = (const float*)d_in[4];
  const float* w_ih_1 = (const float*)d_in[5];
  const float* w_hh_1 = (const float*)d_in[6];
  const float* b_ih_1 = (const float*)d_in[7];
  const float* b_hh_1 = (const float*)d_in[8];
  const float* fc_w0  = (const float*)d_in[9];
  const float* fc_b0  = (const float*)d_in[10];
  const float* fc_w1  = (const float*)d_in[11];
  const float* fc_b1  = (const float*)d_in[12];
  float* out = (float*)d_out;

  // ws: [0,16KB) 64B-padded flags (0xAA poison is negative -> safe);
  //     [16KB, 16KB+1MB) double-buffered h (bf16, 2KB/row)
  int* flags = (int*)d_ws;
  u64* hbuf  = (u64*)((char*)d_ws + 16384);

  size_t shmem = (size_t)NB * L1_RB;  // 66048 B
  hipFuncSetAttribute((const void*)lstm_persist,
                      hipFuncAttributeMaxDynamicSharedMemorySize, (int)shmem);
  hipLaunchKernelGGL(lstm_persist, dim3(256), dim3(256), shmem, stream,
                     u_seq, w_ih_0, w_hh_0, b_ih_0, b_hh_0,
                     w_ih_1, w_hh_1, b_ih_1, b_hh_1,
                     fc_w0, fc_b0, fc_w1, fc_b1, out, flags, hbuf);
}